// Round 10
// baseline (48.324 us; speedup 1.0000x reference)
//
#include <hip/hip_runtime.h>
#include <cstdint>
#include <cstddef>

#define DIMX 512
#define HDIM 32
#define NHEADS 16
#define SEQ 2048
#define BATCH 2
#define MTOT (BATCH*SEQ)   // 4096
#define WIN 64
#define QSCALE 0.17677669529663687f  // 32^-0.5

typedef __bf16 bf16x8 __attribute__((ext_vector_type(8)));
typedef float f32x4 __attribute__((ext_vector_type(4)));

__device__ __forceinline__ unsigned short f2bf(float f){
  unsigned u = __builtin_bit_cast(unsigned, f);
  u += 0x7FFFu + ((u >> 16) & 1u);          // RNE
  return (unsigned short)(u >> 16);
}
__device__ __forceinline__ float bf2f(unsigned short s){
  return __builtin_bit_cast(float, ((unsigned)s) << 16);
}
__device__ __forceinline__ unsigned pk(float a, float b){
  return (unsigned)f2bf(a) | ((unsigned)f2bf(b) << 16);
}

// async global->LDS, 16B per lane; dest is wave-uniform base + lane*16 (HW)
__device__ __forceinline__ void gl_lds16(const void* g, void* l){
  __builtin_amdgcn_global_load_lds(
      (const __attribute__((address_space(1))) unsigned*)g,
      (__attribute__((address_space(3))) unsigned*)(unsigned)(unsigned long long)l,
      16, 0, 0);
}

template<int N> __device__ __forceinline__ void vmwait(){
  if      constexpr (N ==  8) asm volatile("s_waitcnt vmcnt(8)"  ::: "memory");
  else if constexpr (N ==  4) asm volatile("s_waitcnt vmcnt(4)"  ::: "memory");
  else                        asm volatile("s_waitcnt vmcnt(0)"  ::: "memory");
}

// ---------- K0: fused x->bf16 convert + wqt transpose + wotP frag-pack ----------
__global__ void k_prep(const float* __restrict__ x, unsigned short* __restrict__ xb,
                       const float* __restrict__ Wq, unsigned short* __restrict__ Wqt,
                       const float* __restrict__ Wo, unsigned short* __restrict__ WotP){
  int bx = blockIdx.x;
  if (bx < 1024){                      // cvt: 8 elems/thread
    int i = bx * 256 + threadIdx.x;
    const float4* p = (const float4*)x + (size_t)i * 2;
    float4 a = p[0], b = p[1];
    uint4 o;
    o.x = pk(a.x, a.y); o.y = pk(a.z, a.w);
    o.z = pk(b.x, b.y); o.w = pk(b.z, b.w);
    ((uint4*)xb)[i] = o;
    return;
  }
  if (bx < 1536){                      // wqt: W_qkv (512x1024) -> [n][k] bf16
    __shared__ float tile[32][33];
    int i = bx - 1024;                 // 0..511
    int n0 = (i & 31) * 32, k0 = (i >> 5) * 32;
    int tx = threadIdx.x & 31, ty = threadIdx.x >> 5;   // 32x8
    #pragma unroll
    for (int r = 0; r < 32; r += 8)
      tile[ty + r][tx] = Wq[(size_t)(k0 + ty + r) * 1024 + n0 + tx];
    __syncthreads();
    #pragma unroll
    for (int r = 0; r < 32; r += 8)
      Wqt[(size_t)(n0 + ty + r) * 512 + k0 + tx] = f2bf(tile[tx][ty + r]);
    return;
  }
  // wotP: W_out (512x512 [k][n]) -> MFMA-B-fragment-major pack
  // piece (nt 0..31, ks 0..7, kh 0..1, lane): 8 bf16 of (n = nt*16+lane15,
  //   k = ks*64+kh*32+laneh*8 .. +8) stored at [((nt*8+ks)*2+kh)*64 + lane]
  int wid = threadIdx.x >> 6, lane = threadIdx.x & 63;
  int lane15 = lane & 15, laneh = lane >> 4;
  int pair = (bx - 1536) * 4 + wid;    // 0..255
  int nt = pair >> 3, ks = pair & 7;
  int n = nt * 16 + lane15;
  #pragma unroll
  for (int kh = 0; kh < 2; ++kh){
    int k0 = ks * 64 + kh * 32 + laneh * 8;
    unsigned short pc[8];
    #pragma unroll
    for (int j = 0; j < 8; ++j)
      pc[j] = f2bf(Wo[(size_t)(k0 + j) * 512 + n]);
    uint4 o;
    o.x = (unsigned)pc[0] | ((unsigned)pc[1] << 16);
    o.y = (unsigned)pc[2] | ((unsigned)pc[3] << 16);
    o.z = (unsigned)pc[4] | ((unsigned)pc[5] << 16);
    o.w = (unsigned)pc[6] | ((unsigned)pc[7] << 16);
    ((uint4*)WotP)[((size_t)(nt * 8 + ks) * 2 + kh) * 64 + lane] = o;
  }
}

// ---------- K1: QKV bf16 MFMA GEMM, 2-buf depth-1 counted-vmcnt pipeline ----------
// 128x128 block, BK=64, 4 waves (2x2; wave 64x64). Linear LDS dest +
// inverse-swizzled global source + swizzled ds_read (rule #21).
// bn<4 : q=silu*scale, k=tanh -> HEAD-MAJOR [bh][s][32]
// bn>=4: V-tile -> LDS transpose -> vt[bh*32+d][s] + vsum_p partials
template<int BM, int BN, int NBN>
__launch_bounds__(256)
__global__ void k_gemm(const unsigned short* __restrict__ A,
                       const unsigned short* __restrict__ Bt,
                       const float* __restrict__ bias,
                       unsigned short* __restrict__ qb,
                       unsigned short* __restrict__ kb,
                       unsigned short* __restrict__ vt,
                       float* __restrict__ vsum_p)
{
  const int K = 512;
  constexpr int NWG = (MTOT / BM) * NBN;
  constexpr int MF  = BM / 32, NF = BN / 32;   // frags per wave
  constexpr int LPS = (BM + BN) / 32;          // gl_lds per thread per K-step
  __shared__ __align__(16) unsigned short lds[2][(BM + BN) * 64];
  int tid = threadIdx.x;
  int wid = tid >> 6, lane = tid & 63;
  int wm = wid >> 1, wn = wid & 1;
  int lane15 = lane & 15, laneh = lane >> 4;

  // XCD-aware bijective swizzle (NWG % 8 == 0)
  int g = blockIdx.x;
  int gwi = (g & 7) * (NWG / 8) + (g >> 3);
  int bm = gwi / NBN, bn = gwi % NBN;

  f32x4 acc[MF][NF] = {};

  int srow_off = lane >> 3;           // 0..7
  int spos     = lane & 7;            // 0..7

  auto STAGE = [&](int buf, int kt){
    int k0 = kt * 64;
    #pragma unroll
    for (int c = 0; c < MF; ++c){
      int cidx = wid * MF + c;
      int r = cidx * 8 + srow_off;
      int ch = spos ^ (r & 7);
      gl_lds16(A + (size_t)(bm * BM + r) * K + k0 + ch * 8, &lds[buf][cidx * 512]);
    }
    #pragma unroll
    for (int c = 0; c < NF; ++c){
      int cidx = wid * NF + c;
      int r = cidx * 8 + srow_off;
      int ch = spos ^ (r & 7);
      gl_lds16(Bt + (size_t)(bn * BN + r) * K + k0 + ch * 8, &lds[buf][BM * 64 + cidx * 512]);
    }
  };

  auto COMPUTE = [&](int buf){
    #pragma unroll
    for (int kh = 0; kh < 2; ++kh){
      int chunk = kh * 4 + laneh;
      bf16x8 af[MF], bfv[NF];
      #pragma unroll
      for (int mi = 0; mi < MF; ++mi){
        int row = wm * (BM / 2) + mi * 16 + lane15;
        af[mi] = *(const bf16x8*)&lds[buf][row * 64 + (chunk ^ (row & 7)) * 8];
      }
      #pragma unroll
      for (int ni = 0; ni < NF; ++ni){
        int row = wn * (BN / 2) + ni * 16 + lane15;
        bfv[ni] = *(const bf16x8*)&lds[buf][BM * 64 + row * 64 + (chunk ^ (row & 7)) * 8];
      }
      #pragma unroll
      for (int mi = 0; mi < MF; ++mi)
        #pragma unroll
        for (int ni = 0; ni < NF; ++ni)
          acc[mi][ni] = __builtin_amdgcn_mfma_f32_16x16x32_bf16(af[mi], bfv[ni], acc[mi][ni], 0, 0, 0);
    }
  };

  STAGE(0, 0);
  #pragma unroll
  for (int kt = 0; kt < 8; ++kt){
    if (kt < 7) STAGE((kt + 1) & 1, kt + 1);
    if (kt < 7) vmwait<LPS>(); else vmwait<0>();
    __builtin_amdgcn_s_barrier();
    __builtin_amdgcn_sched_barrier(0);
    COMPUTE(kt & 1);
    __builtin_amdgcn_s_barrier();
    __builtin_amdgcn_sched_barrier(0);
  }

  if (bn >= 4){
    // ---- V path: transpose 128x128 tile in LDS, write vt + vsum partials ----
    unsigned short (*tp)[136] = (unsigned short (*)[136])&lds[0][0];
    #pragma unroll
    for (int mi = 0; mi < MF; ++mi)
      #pragma unroll
      for (int ni = 0; ni < NF; ++ni)
        #pragma unroll
        for (int r = 0; r < 4; ++r){
          int ml = wm * (BM / 2) + mi * 16 + laneh * 4 + r;
          int nl = wn * (BN / 2) + ni * 16 + lane15;
          tp[nl][ml] = f2bf(acc[mi][ni][r] + bias[bn * BN + nl]);
        }
    __syncthreads();
    int nl = tid >> 1, half = tid & 1;
    int h = (bn - 4) * 4 + (nl >> 5), d = nl & 31;
    int b = bm >> 4, sc = bm & 15;
    int bh = b * 16 + h;
    uint4 v4[8];
    float ssum = 0.f;
    #pragma unroll
    for (int p = 0; p < 8; ++p){
      v4[p] = *(const uint4*)&tp[nl][half * 64 + p * 8];
      const unsigned* w = (const unsigned*)&v4[p];
      #pragma unroll
      for (int j = 0; j < 4; ++j)
        ssum += bf2f((unsigned short)(w[j] & 0xffff)) + bf2f((unsigned short)(w[j] >> 16));
    }
    ssum += __shfl_xor(ssum, 1);
    size_t vtoff = (size_t)(bh * HDIM + d) * SEQ + sc * 128 + half * 64;
    #pragma unroll
    for (int p = 0; p < 8; ++p) *(uint4*)(vt + vtoff + p * 8) = v4[p];
    if (half == 0) vsum_p[(sc * 32 + bh) * HDIM + d] = ssum;
  } else {
    #pragma unroll
    for (int mi = 0; mi < MF; ++mi){
      #pragma unroll
      for (int ni = 0; ni < NF; ++ni){
        #pragma unroll
        for (int r = 0; r < 4; ++r){
          int m = bm * BM + wm * (BM / 2) + mi * 16 + laneh * 4 + r;
          int n = bn * BN + wn * (BN / 2) + ni * 16 + lane15;
          float val = acc[mi][ni][r] + bias[n];
          int b = m >> 11, s = m & 2047;
          int h = n >> 5, d = n & 31;
          size_t idx = ((size_t)(b * 16 + h) * SEQ + s) * HDIM + d;
          float sv = val / (1.0f + __expf(-val)) * QSCALE;      // silu * scale
          float tv = 1.0f - 2.0f / (1.0f + __expf(2.0f * val)); // tanh
          qb[idx] = f2bf(sv);
          kb[idx] = f2bf(tv);
        }
      }
    }
  }
}

// ---------- K2: banded attention (e^s - 1 trick), MFMA, 9 k-tiles ----------
__launch_bounds__(256)
__global__ void k_attn(const unsigned short* __restrict__ qb,
                       const unsigned short* __restrict__ kb,
                       const unsigned short* __restrict__ vt,
                       const float* __restrict__ vsum_p,
                       unsigned short* __restrict__ ao)
{
  __shared__ unsigned short p_lds[4][16][40];
  int tid = threadIdx.x, wid = tid >> 6, lane = tid & 63;
  int lane15 = lane & 15, laneh = lane >> 4;
  int bh = blockIdx.y, b = bh >> 4, h = bh & 15;
  int s0 = blockIdx.x * 64 + wid * 16;

  bf16x8 qf = *(const bf16x8*)(qb + ((size_t)bh * SEQ + s0 + lane15) * HDIM + laneh * 8);
  float vs0 = 0.f, vs1 = 0.f;
  #pragma unroll
  for (int c = 0; c < 16; ++c){
    vs0 += vsum_p[(c * 32 + bh) * HDIM + lane15];
    vs1 += vsum_p[(c * 32 + bh) * HDIM + 16 + lane15];
  }

  f32x4 accv[2] = {};
  float dsum[4] = {0.f, 0.f, 0.f, 0.f};

  for (int jt = 0; jt < 9; ++jt){
    int j0 = s0 - 64 + jt * 16;
    int jc = min(max(j0 + lane15, 0), SEQ - 1);
    bf16x8 kf = *(const bf16x8*)(kb + ((size_t)bh * SEQ + jc) * HDIM + laneh * 8);
    f32x4 z = {0.f, 0.f, 0.f, 0.f};
    f32x4 sv = __builtin_amdgcn_mfma_f32_16x16x32_bf16(qf, kf, z, 0, 0, 0);
    #pragma unroll
    for (int r = 0; r < 4; ++r){
      int i = s0 + laneh * 4 + r;
      int j = j0 + lane15;
      int dj = i - j;
      bool inb = (dj <= WIN) && (dj >= -WIN) && (j >= 0) && (j < SEQ);
      float w = inb ? (__expf(sv[r]) - 1.0f) : 0.0f;
      dsum[r] += w;
      p_lds[wid][laneh * 4 + r][(jt & 1) * 16 + lane15] = f2bf(w);
    }
    if (jt & 1){
      int jc0 = j0 - 16;
      bf16x8 pa = *(const bf16x8*)&p_lds[wid][lane15][laneh * 8];
      int jv = min(max(jc0 + laneh * 8, 0), SEQ - 8);
      bf16x8 v0 = *(const bf16x8*)(vt + (size_t)(bh * HDIM + lane15) * SEQ + jv);
      bf16x8 v1 = *(const bf16x8*)(vt + (size_t)(bh * HDIM + 16 + lane15) * SEQ + jv);
      accv[0] = __builtin_amdgcn_mfma_f32_16x16x32_bf16(pa, v0, accv[0], 0, 0, 0);
      accv[1] = __builtin_amdgcn_mfma_f32_16x16x32_bf16(pa, v1, accv[1], 0, 0, 0);
    }
  }
  {
    #pragma unroll
    for (int r = 0; r < 4; ++r)
      p_lds[wid][laneh * 4 + r][16 + lane15] = 0;
    int jc0 = s0 + 64;
    bf16x8 pa = *(const bf16x8*)&p_lds[wid][lane15][laneh * 8];
    int jv = min(max(jc0 + laneh * 8, 0), SEQ - 8);
    bf16x8 v0 = *(const bf16x8*)(vt + (size_t)(bh * HDIM + lane15) * SEQ + jv);
    bf16x8 v1 = *(const bf16x8*)(vt + (size_t)(bh * HDIM + 16 + lane15) * SEQ + jv);
    accv[0] = __builtin_amdgcn_mfma_f32_16x16x32_bf16(pa, v0, accv[0], 0, 0, 0);
    accv[1] = __builtin_amdgcn_mfma_f32_16x16x32_bf16(pa, v1, accv[1], 0, 0, 0);
  }

  #pragma unroll
  for (int r = 0; r < 4; ++r){
    float v = dsum[r];
    v += __shfl_xor(v, 1); v += __shfl_xor(v, 2);
    v += __shfl_xor(v, 4); v += __shfl_xor(v, 8);
    dsum[r] = v;
  }
  #pragma unroll
  for (int r = 0; r < 4; ++r){
    int i = s0 + laneh * 4 + r;
    float dn = (float)SEQ + dsum[r];
    float o0 = (accv[0][r] + vs0) / dn;
    float o1 = (accv[1][r] + vs1) / dn;
    size_t base = (size_t)(b * SEQ + i) * DIMX + h * HDIM;
    ao[base + lane15]      = f2bf(o0);
    ao[base + 16 + lane15] = f2bf(o1);
  }
}

// ---------- K3: fused out-proj + residual + LayerNorm ----------
// 256 blocks x 512 threads; block owns 16 full rows. A (ao tile) in LDS
// (swizzled source), B (wotP) fragment-major direct from L2 to VGPRs.
__launch_bounds__(512)
__global__ void k_oln(const unsigned short* __restrict__ ao,
                      const unsigned short* __restrict__ wotP,
                      const float* __restrict__ bout,
                      const unsigned short* __restrict__ xb,
                      const float* __restrict__ gamma,
                      const float* __restrict__ beta,
                      float* __restrict__ out)
{
  __shared__ __align__(16) unsigned short asA[16 * 520];
  __shared__ float tp[16][516];
  int tid = threadIdx.x;
  int wid = tid >> 6, lane = tid & 63;
  int lane15 = lane & 15, laneh = lane >> 4;
  int mrow0 = blockIdx.x * 16;

  // stage A: row = wid*2+c; LDS pos p = lane holds source chunk (lane ^ (row&7))
  #pragma unroll
  for (int c = 0; c < 2; ++c){
    int row = wid * 2 + c;
    gl_lds16(ao + (size_t)(mrow0 + row) * DIMX + (lane ^ (row & 7)) * 8,
             &asA[row * 520]);
  }

  f32x4 acc[4] = {};
  const uint4* bp = (const uint4*)wotP;

  __syncthreads();   // drains vmcnt(0): A tile resident

  #pragma unroll
  for (int kt = 0; kt < 8; ++kt){
    #pragma unroll
    for (int kh = 0; kh < 2; ++kh){
      int ck = kt * 8 + kh * 4 + laneh;
      bf16x8 af = *(const bf16x8*)&asA[lane15 * 520 + ((ck ^ (lane15 & 7)) * 8)];
      #pragma unroll
      for (int ni = 0; ni < 4; ++ni){
        uint4 braw = bp[((size_t)((wid * 4 + ni) * 8 + kt) * 2 + kh) * 64 + lane];
        acc[ni] = __builtin_amdgcn_mfma_f32_16x16x32_bf16(
                     af, __builtin_bit_cast(bf16x8, braw), acc[ni], 0, 0, 0);
      }
    }
  }

  // bias + transpose accumulators into tp (fp32)
  #pragma unroll
  for (int ni = 0; ni < 4; ++ni){
    int col = wid * 64 + ni * 16 + lane15;
    float bv = bout[col];
    #pragma unroll
    for (int r = 0; r < 4; ++r)
      tp[laneh * 4 + r][col] = acc[ni][r] + bv;
  }
  __syncthreads();

  // each thread: one row (tr) x 16-col segment (seg); residual + LN
  int tr = tid >> 5, seg = tid & 31;
  const unsigned short* xr = xb + (size_t)(mrow0 + tr) * DIMX + seg * 16;
  uint4 x0 = *(const uint4*)xr, x1 = *(const uint4*)(xr + 8);
  unsigned xwv[8];
  *(uint4*)&xwv[0] = x0; *(uint4*)&xwv[4] = x1;
  float v[16], s = 0.f, ss = 0.f;
  #pragma unroll
  for (int j = 0; j < 16; ++j){
    unsigned wb = xwv[j >> 1];
    unsigned short hv = (j & 1) ? (unsigned short)(wb >> 16) : (unsigned short)(wb & 0xffff);
    v[j] = tp[tr][seg * 16 + j] + bf2f(hv);
    s += v[j]; ss += v[j] * v[j];
  }
  #pragma unroll
  for (int m = 1; m < 32; m <<= 1){ s += __shfl_xor(s, m); ss += __shfl_xor(ss, m); }
  float mu  = s * (1.f / DIMX);
  float var = ss * (1.f / DIMX) - mu * mu;
  float inv = rsqrtf(var + 1e-5f);
  float* op = out + (size_t)(mrow0 + tr) * DIMX + seg * 16;
  const float* gp = gamma + seg * 16;
  const float* bb = beta  + seg * 16;
  #pragma unroll
  for (int j = 0; j < 16; ++j)
    op[j] = (v[j] - mu) * inv * gp[j] + bb[j];
}

extern "C" void kernel_launch(void* const* d_in, const int* in_sizes, int n_in,
                              void* d_out, int out_size, void* d_ws, size_t ws_size,
                              hipStream_t stream){
  const float* x      = (const float*)d_in[0];
  const float* W_qkv  = (const float*)d_in[1];
  const float* b_qkv  = (const float*)d_in[2];
  const float* W_out  = (const float*)d_in[3];
  const float* b_out  = (const float*)d_in[4];
  const float* gamma  = (const float*)d_in[5];
  const float* beta   = (const float*)d_in[6];
  float* out = (float*)d_out;

  char* ws = (char*)d_ws;
  size_t off = 0;
  auto alloc = [&](size_t bytes){ void* p = ws + off; off += (bytes + 255) & ~(size_t)255; return p; };
  unsigned short* xb   = (unsigned short*)alloc((size_t)MTOT * DIMX * 2);
  unsigned short* wqt  = (unsigned short*)alloc((size_t)1024 * 512 * 2);
  unsigned short* wotP = (unsigned short*)alloc((size_t)512 * 512 * 2);
  unsigned short* qb   = (unsigned short*)alloc((size_t)MTOT * DIMX * 2);
  unsigned short* kb   = (unsigned short*)alloc((size_t)MTOT * DIMX * 2);
  unsigned short* vt   = (unsigned short*)alloc((size_t)32 * HDIM * SEQ * 2);
  float*          vsm  = (float*)alloc((size_t)16 * 32 * HDIM * 4);
  unsigned short* ao   = (unsigned short*)alloc((size_t)MTOT * DIMX * 2);

  k_prep<<<1600, 256, 0, stream>>>(x, xb, W_qkv, wqt, W_out, wotP);
  k_gemm<128, 128, 8><<<256, 256, 0, stream>>>(xb, wqt, b_qkv, qb, kb, vt, vsm);
  k_attn<<<dim3(32, 32), 256, 0, stream>>>(qb, kb, vt, vsm, ao);
  k_oln <<<256, 512, 0, stream>>>(ao, wotP, b_out, xb, gamma, beta, out);
}

// Round 11
// 44.954 us; speedup vs baseline: 1.0750x; 1.0750x over previous
//
#include <hip/hip_runtime.h>
#include <cstdint>
#include <cstddef>

#define DIMX 512
#define HDIM 32
#define NHEADS 16
#define SEQ 2048
#define BATCH 2
#define MTOT (BATCH*SEQ)   // 4096
#define WIN 64
#define QSCALE 0.17677669529663687f  // 32^-0.5

typedef __bf16 bf16x8 __attribute__((ext_vector_type(8)));
typedef float f32x4 __attribute__((ext_vector_type(4)));

__device__ __forceinline__ unsigned short f2bf(float f){
  unsigned u = __builtin_bit_cast(unsigned, f);
  u += 0x7FFFu + ((u >> 16) & 1u);          // RNE
  return (unsigned short)(u >> 16);
}
__device__ __forceinline__ float bf2f(unsigned short s){
  return __builtin_bit_cast(float, ((unsigned)s) << 16);
}
__device__ __forceinline__ unsigned pk(float a, float b){
  return (unsigned)f2bf(a) | ((unsigned)f2bf(b) << 16);
}

// async global->LDS, 16B per lane; dest is wave-uniform base + lane*16 (HW)
__device__ __forceinline__ void gl_lds16(const void* g, void* l){
  __builtin_amdgcn_global_load_lds(
      (const __attribute__((address_space(1))) unsigned*)g,
      (__attribute__((address_space(3))) unsigned*)(unsigned)(unsigned long long)l,
      16, 0, 0);
}

template<int N> __device__ __forceinline__ void vmwait(){
  if      constexpr (N == 16) asm volatile("s_waitcnt vmcnt(16)" ::: "memory");
  else if constexpr (N ==  8) asm volatile("s_waitcnt vmcnt(8)"  ::: "memory");
  else if constexpr (N ==  4) asm volatile("s_waitcnt vmcnt(4)"  ::: "memory");
  else                        asm volatile("s_waitcnt vmcnt(0)"  ::: "memory");
}

// ---------- K0: fused x->bf16 convert (blocks 0..1023) + weight transposes ----------
__global__ void k_prep(const float* __restrict__ x, unsigned short* __restrict__ xb,
                       const float* __restrict__ Wq, unsigned short* __restrict__ Wqt,
                       const float* __restrict__ Wo, unsigned short* __restrict__ Wot){
  int bx = blockIdx.x;
  if (bx < 1024){                      // cvt: 8 elems/thread
    int i = bx * 256 + threadIdx.x;
    const float4* p = (const float4*)x + (size_t)i * 2;
    float4 a = p[0], b = p[1];
    uint4 o;
    o.x = pk(a.x, a.y); o.y = pk(a.z, a.w);
    o.z = pk(b.x, b.y); o.w = pk(b.z, b.w);
    ((uint4*)xb)[i] = o;
    return;
  }
  __shared__ float tile[32][33];
  int i = bx - 1024;                   // 0..767 -> (bxx 0..47, byy 0..15)
  int bxx = i % 48, byy = i / 48;
  const float* W; unsigned short* Wt; int N, n0;
  if (bxx < 32){ W = Wq; Wt = Wqt; N = 1024; n0 = bxx * 32; }
  else         { W = Wo; Wt = Wot; N = 512;  n0 = (bxx - 32) * 32; }
  int k0 = byy * 32;
  int tx = threadIdx.x & 31, ty = threadIdx.x >> 5;   // 32x8
  #pragma unroll
  for (int r = 0; r < 32; r += 8)
    tile[ty + r][tx] = W[(size_t)(k0 + ty + r) * N + n0 + tx];
  __syncthreads();
  #pragma unroll
  for (int r = 0; r < 32; r += 8)
    Wt[(size_t)(n0 + ty + r) * 512 + k0 + tx] = f2bf(tile[tx][ty + r]);
}

// ---------- K1/K4: bf16 MFMA GEMM, 3-buf depth-2 counted-vmcnt pipeline ----------
// BM x BN block, BK=64, 4 waves (2x2; wave = BM/2 x BN/2). Linear LDS dest +
// inverse-swizzled global source + swizzled ds_read (rule #21).
// Loads for steps kt+1, kt+2 stay in flight across barriers (T4, R8-proven).
// MODE 0 (128x128): bn<4: q=silu*scale, k=tanh -> HEAD-MAJOR [bh][s][32]
//                   bn>=4: V-tile -> LDS transpose -> vt[bh*32+d][s] + vsum_p
// MODE 1 (64x64)  : yb = bf16(acc + bias + xb)
template<int MODE, int BM, int BN, int NBN>
__launch_bounds__(256)
__global__ void k_gemm(const unsigned short* __restrict__ A,
                       const unsigned short* __restrict__ Bt,
                       const float* __restrict__ bias,
                       unsigned short* __restrict__ qb,
                       unsigned short* __restrict__ kb,
                       unsigned short* __restrict__ vt,
                       float* __restrict__ vsum_p,
                       const unsigned short* __restrict__ xb,
                       unsigned short* __restrict__ yb)
{
  const int K = 512;
  constexpr int NWG = (MTOT / BM) * NBN;
  constexpr int MF  = BM / 32, NF = BN / 32;   // frags per wave
  constexpr int LPS = (BM + BN) / 32;          // gl_lds per thread per K-step
  __shared__ __align__(16) unsigned short lds[3][(BM + BN) * 64];
  int tid = threadIdx.x;
  int wid = tid >> 6, lane = tid & 63;
  int wm = wid >> 1, wn = wid & 1;
  int lane15 = lane & 15, laneh = lane >> 4;

  // XCD-aware bijective swizzle (NWG % 8 == 0)
  int g = blockIdx.x;
  int gwi = (g & 7) * (NWG / 8) + (g >> 3);
  int bm = gwi / NBN, bn = gwi % NBN;

  f32x4 acc[MF][NF] = {};

  int srow_off = lane >> 3;           // 0..7
  int spos     = lane & 7;            // 0..7

  auto STAGE = [&](int buf, int kt){
    int k0 = kt * 64;
    #pragma unroll
    for (int c = 0; c < MF; ++c){
      int cidx = wid * MF + c;
      int r = cidx * 8 + srow_off;
      int ch = spos ^ (r & 7);
      gl_lds16(A + (size_t)(bm * BM + r) * K + k0 + ch * 8, &lds[buf][cidx * 512]);
    }
    #pragma unroll
    for (int c = 0; c < NF; ++c){
      int cidx = wid * NF + c;
      int r = cidx * 8 + srow_off;
      int ch = spos ^ (r & 7);
      gl_lds16(Bt + (size_t)(bn * BN + r) * K + k0 + ch * 8, &lds[buf][BM * 64 + cidx * 512]);
    }
  };

  auto COMPUTE = [&](int buf){
    #pragma unroll
    for (int kh = 0; kh < 2; ++kh){
      int chunk = kh * 4 + laneh;
      bf16x8 af[MF], bfv[NF];
      #pragma unroll
      for (int mi = 0; mi < MF; ++mi){
        int row = wm * (BM / 2) + mi * 16 + lane15;
        af[mi] = *(const bf16x8*)&lds[buf][row * 64 + (chunk ^ (row & 7)) * 8];
      }
      #pragma unroll
      for (int ni = 0; ni < NF; ++ni){
        int row = wn * (BN / 2) + ni * 16 + lane15;
        bfv[ni] = *(const bf16x8*)&lds[buf][BM * 64 + row * 64 + (chunk ^ (row & 7)) * 8];
      }
      #pragma unroll
      for (int mi = 0; mi < MF; ++mi)
        #pragma unroll
        for (int ni = 0; ni < NF; ++ni)
          acc[mi][ni] = __builtin_amdgcn_mfma_f32_16x16x32_bf16(af[mi], bfv[ni], acc[mi][ni], 0, 0, 0);
    }
  };

  // 3-buffer, depth-2 prefetch; counted vmcnt keeps 2 tiles' loads in flight.
  STAGE(0, 0);
  STAGE(1, 1);
  #pragma unroll
  for (int kt = 0; kt < 8; ++kt){
    if (kt < 6) STAGE((kt + 2) % 3, kt + 2);
    if (kt < 6)       vmwait<2 * LPS>();
    else if (kt == 6) vmwait<LPS>();
    else              vmwait<0>();
    __builtin_amdgcn_s_barrier();          // buf kt fully staged for all waves
    __builtin_amdgcn_sched_barrier(0);
    COMPUTE(kt % 3);
    __builtin_amdgcn_s_barrier();          // all waves done reading buf kt
    __builtin_amdgcn_sched_barrier(0);
  }

  if (MODE == 0 && bn >= 4){
    // ---- V path: transpose 128x128 tile in LDS, write vt + vsum partials ----
    unsigned short (*tp)[136] = (unsigned short (*)[136])&lds[0][0];  // 34.8 KB
    #pragma unroll
    for (int mi = 0; mi < MF; ++mi)
      #pragma unroll
      for (int ni = 0; ni < NF; ++ni)
        #pragma unroll
        for (int r = 0; r < 4; ++r){
          int ml = wm * (BM / 2) + mi * 16 + laneh * 4 + r;
          int nl = wn * (BN / 2) + ni * 16 + lane15;
          tp[nl][ml] = f2bf(acc[mi][ni][r] + bias[bn * BN + nl]);
        }
    __syncthreads();
    int nl = tid >> 1, half = tid & 1;    // nl 0..127, half covers 64 s each
    int h = (bn - 4) * 4 + (nl >> 5), d = nl & 31;
    int b = bm >> 4, sc = bm & 15;        // 128-row s-chunk within batch
    int bh = b * 16 + h;
    uint4 v4[8];
    float ssum = 0.f;
    #pragma unroll
    for (int p = 0; p < 8; ++p){
      v4[p] = *(const uint4*)&tp[nl][half * 64 + p * 8];
      const unsigned* w = (const unsigned*)&v4[p];
      #pragma unroll
      for (int j = 0; j < 4; ++j)
        ssum += bf2f((unsigned short)(w[j] & 0xffff)) + bf2f((unsigned short)(w[j] >> 16));
    }
    ssum += __shfl_xor(ssum, 1);          // combine the two halves
    size_t vtoff = (size_t)(bh * HDIM + d) * SEQ + sc * 128 + half * 64;
    #pragma unroll
    for (int p = 0; p < 8; ++p) *(uint4*)(vt + vtoff + p * 8) = v4[p];
    if (half == 0) vsum_p[(sc * 32 + bh) * HDIM + d] = ssum;
  } else {
    #pragma unroll
    for (int mi = 0; mi < MF; ++mi){
      #pragma unroll
      for (int ni = 0; ni < NF; ++ni){
        #pragma unroll
        for (int r = 0; r < 4; ++r){
          int m = bm * BM + wm * (BM / 2) + mi * 16 + laneh * 4 + r;
          int nloc = wn * (BN / 2) + ni * 16 + lane15;
          int n = bn * BN + nloc;
          float val = acc[mi][ni][r] + bias[n];
          if (MODE == 0){
            // head-major q/k: [bh][s][32]
            int b = m >> 11, s = m & 2047;
            int h = n >> 5, d = n & 31;
            size_t idx = ((size_t)(b * 16 + h) * SEQ + s) * HDIM + d;
            float sv = val / (1.0f + __expf(-val)) * QSCALE;      // silu * scale
            float tv = 1.0f - 2.0f / (1.0f + __expf(2.0f * val)); // tanh
            qb[idx] = f2bf(sv);
            kb[idx] = f2bf(tv);
          } else {
            size_t idx = (size_t)m * DIMX + n;
            yb[idx] = f2bf(val + bf2f(xb[idx]));
          }
        }
      }
    }
  }
}

// ---------- K3: banded attention (e^s - 1 trick), MFMA, 9 k-tiles ----------
// q/k head-major [bh][s][32]: fully coalesced 1KB loads per instr.
__launch_bounds__(256)
__global__ void k_attn(const unsigned short* __restrict__ qb,
                       const unsigned short* __restrict__ kb,
                       const unsigned short* __restrict__ vt,
                       const float* __restrict__ vsum_p,
                       unsigned short* __restrict__ ao)
{
  __shared__ unsigned short p_lds[4][16][40];   // per-wave P staging, padded
  int tid = threadIdx.x, wid = tid >> 6, lane = tid & 63;
  int lane15 = lane & 15, laneh = lane >> 4;
  int bh = blockIdx.y, b = bh >> 4, h = bh & 15;
  int s0 = blockIdx.x * 64 + wid * 16;

  bf16x8 qf = *(const bf16x8*)(qb + ((size_t)bh * SEQ + s0 + lane15) * HDIM + laneh * 8);
  float vs0 = 0.f, vs1 = 0.f;
  #pragma unroll
  for (int c = 0; c < 16; ++c){
    vs0 += vsum_p[(c * 32 + bh) * HDIM + lane15];
    vs1 += vsum_p[(c * 32 + bh) * HDIM + 16 + lane15];
  }

  f32x4 accv[2] = {};
  float dsum[4] = {0.f, 0.f, 0.f, 0.f};

  // band |i-j|<=64 with i in [s0, s0+16) touches j in [s0-64, s0+80) = 9 tiles
  for (int jt = 0; jt < 9; ++jt){
    int j0 = s0 - 64 + jt * 16;
    int jc = min(max(j0 + lane15, 0), SEQ - 1);
    bf16x8 kf = *(const bf16x8*)(kb + ((size_t)bh * SEQ + jc) * HDIM + laneh * 8);
    f32x4 z = {0.f, 0.f, 0.f, 0.f};
    f32x4 sv = __builtin_amdgcn_mfma_f32_16x16x32_bf16(qf, kf, z, 0, 0, 0);
    #pragma unroll
    for (int r = 0; r < 4; ++r){
      int i = s0 + laneh * 4 + r;
      int j = j0 + lane15;
      int dj = i - j;
      bool inb = (dj <= WIN) && (dj >= -WIN) && (j >= 0) && (j < SEQ);
      float w = inb ? (__expf(sv[r]) - 1.0f) : 0.0f;
      dsum[r] += w;
      p_lds[wid][laneh * 4 + r][(jt & 1) * 16 + lane15] = f2bf(w);
    }
    if (jt & 1){
      int jc0 = j0 - 16;   // 32-wide chunk base
      bf16x8 pa = *(const bf16x8*)&p_lds[wid][lane15][laneh * 8];
      int jv = min(max(jc0 + laneh * 8, 0), SEQ - 8);
      bf16x8 v0 = *(const bf16x8*)(vt + (size_t)(bh * HDIM + lane15) * SEQ + jv);
      bf16x8 v1 = *(const bf16x8*)(vt + (size_t)(bh * HDIM + 16 + lane15) * SEQ + jv);
      accv[0] = __builtin_amdgcn_mfma_f32_16x16x32_bf16(pa, v0, accv[0], 0, 0, 0);
      accv[1] = __builtin_amdgcn_mfma_f32_16x16x32_bf16(pa, v1, accv[1], 0, 0, 0);
    }
  }
  // tail PV for tile 8 (cols 0..15); zero cols 16..31 first
  {
    #pragma unroll
    for (int r = 0; r < 4; ++r)
      p_lds[wid][laneh * 4 + r][16 + lane15] = 0;
    int jc0 = s0 + 64;
    bf16x8 pa = *(const bf16x8*)&p_lds[wid][lane15][laneh * 8];
    int jv = min(max(jc0 + laneh * 8, 0), SEQ - 8);
    bf16x8 v0 = *(const bf16x8*)(vt + (size_t)(bh * HDIM + lane15) * SEQ + jv);
    bf16x8 v1 = *(const bf16x8*)(vt + (size_t)(bh * HDIM + 16 + lane15) * SEQ + jv);
    accv[0] = __builtin_amdgcn_mfma_f32_16x16x32_bf16(pa, v0, accv[0], 0, 0, 0);
    accv[1] = __builtin_amdgcn_mfma_f32_16x16x32_bf16(pa, v1, accv[1], 0, 0, 0);
  }

  #pragma unroll
  for (int r = 0; r < 4; ++r){
    float v = dsum[r];
    v += __shfl_xor(v, 1); v += __shfl_xor(v, 2);
    v += __shfl_xor(v, 4); v += __shfl_xor(v, 8);
    dsum[r] = v;
  }
  #pragma unroll
  for (int r = 0; r < 4; ++r){
    int i = s0 + laneh * 4 + r;
    float dn = (float)SEQ + dsum[r];
    float o0 = (accv[0][r] + vs0) / dn;
    float o1 = (accv[1][r] + vs1) / dn;
    size_t base = (size_t)(b * SEQ + i) * DIMX + h * HDIM;
    ao[base + lane15]      = f2bf(o0);
    ao[base + 16 + lane15] = f2bf(o1);
  }
}

// ---------- K5: LayerNorm over 512 (bf16 in, fp32 out), one wave per row ----------
__global__ void k_ln(const unsigned short* __restrict__ yb, const float* __restrict__ gamma,
                     const float* __restrict__ beta, float* __restrict__ out){
  int wid = threadIdx.x >> 6, lane = threadIdx.x & 63;
  int row = blockIdx.x * 4 + wid;
  uint4 u = *(const uint4*)(yb + (size_t)row * DIMX + lane * 8);
  const unsigned* w = (const unsigned*)&u;
  float v[8];
  #pragma unroll
  for (int j = 0; j < 4; ++j){
    v[2*j]   = bf2f((unsigned short)(w[j] & 0xffff));
    v[2*j+1] = bf2f((unsigned short)(w[j] >> 16));
  }
  float s = 0.f, ss = 0.f;
  #pragma unroll
  for (int j = 0; j < 8; ++j){ s += v[j]; ss += v[j] * v[j]; }
  #pragma unroll
  for (int m = 1; m < 64; m <<= 1){ s += __shfl_xor(s, m); ss += __shfl_xor(ss, m); }
  float mu = s * (1.f / DIMX);
  float var = ss * (1.f / DIMX) - mu * mu;
  float inv = rsqrtf(var + 1e-5f);
  float4 g0 = *(const float4*)(gamma + lane * 8);
  float4 g1 = *(const float4*)(gamma + lane * 8 + 4);
  float4 b0 = *(const float4*)(beta + lane * 8);
  float4 b1 = *(const float4*)(beta + lane * 8 + 4);
  float4 o0, o1;
  o0.x = (v[0] - mu) * inv * g0.x + b0.x; o0.y = (v[1] - mu) * inv * g0.y + b0.y;
  o0.z = (v[2] - mu) * inv * g0.z + b0.z; o0.w = (v[3] - mu) * inv * g0.w + b0.w;
  o1.x = (v[4] - mu) * inv * g1.x + b1.x; o1.y = (v[5] - mu) * inv * g1.y + b1.y;
  o1.z = (v[6] - mu) * inv * g1.z + b1.z; o1.w = (v[7] - mu) * inv * g1.w + b1.w;
  float* op = out + (size_t)row * DIMX + lane * 8;
  *(float4*)op = o0; *(float4*)(op + 4) = o1;
}

extern "C" void kernel_launch(void* const* d_in, const int* in_sizes, int n_in,
                              void* d_out, int out_size, void* d_ws, size_t ws_size,
                              hipStream_t stream){
  const float* x      = (const float*)d_in[0];
  const float* W_qkv  = (const float*)d_in[1];
  const float* b_qkv  = (const float*)d_in[2];
  const float* W_out  = (const float*)d_in[3];
  const float* b_out  = (const float*)d_in[4];
  const float* gamma  = (const float*)d_in[5];
  const float* beta   = (const float*)d_in[6];
  float* out = (float*)d_out;

  char* ws = (char*)d_ws;
  size_t off = 0;
  auto alloc = [&](size_t bytes){ void* p = ws + off; off += (bytes + 255) & ~(size_t)255; return p; };
  unsigned short* xb  = (unsigned short*)alloc((size_t)MTOT * DIMX * 2);
  unsigned short* wqt = (unsigned short*)alloc((size_t)1024 * 512 * 2);
  unsigned short* wot = (unsigned short*)alloc((size_t)512 * 512 * 2);
  unsigned short* qb  = (unsigned short*)alloc((size_t)MTOT * DIMX * 2);
  unsigned short* kb  = (unsigned short*)alloc((size_t)MTOT * DIMX * 2);
  unsigned short* vt  = (unsigned short*)alloc((size_t)32 * HDIM * SEQ * 2);
  float*          vsm = (float*)alloc((size_t)16 * 32 * HDIM * 4);
  unsigned short* ao  = (unsigned short*)alloc((size_t)MTOT * DIMX * 2);
  unsigned short* yb  = (unsigned short*)alloc((size_t)MTOT * DIMX * 2);

  k_prep<<<1792, 256, 0, stream>>>(x, xb, W_qkv, wqt, W_out, wot);
  k_gemm<0, 128, 128, 8><<<256, 256, 0, stream>>>(xb, wqt, b_qkv, qb, kb, vt, vsm, nullptr, nullptr);
  k_attn<<<dim3(32, 32), 256, 0, stream>>>(qb, kb, vt, vsm, ao);
  k_gemm<1, 64, 64, 8><<<512, 256, 0, stream>>>(ao, wot, b_out, nullptr, nullptr, nullptr, nullptr, xb, yb);
  k_ln  <<<MTOT / 4, 256, 0, stream>>>(yb, gamma, beta, out);
}

// Round 12
// 43.881 us; speedup vs baseline: 1.1013x; 1.0245x over previous
//
#include <hip/hip_runtime.h>
#include <cstdint>
#include <cstddef>

#define DIMX 512
#define HDIM 32
#define NHEADS 16
#define SEQ 2048
#define BATCH 2
#define MTOT (BATCH*SEQ)   // 4096
#define WIN 64
#define QSCALE 0.17677669529663687f  // 32^-0.5

typedef __bf16 bf16x8 __attribute__((ext_vector_type(8)));
typedef float f32x4 __attribute__((ext_vector_type(4)));

__device__ __forceinline__ unsigned short f2bf(float f){
  unsigned u = __builtin_bit_cast(unsigned, f);
  u += 0x7FFFu + ((u >> 16) & 1u);          // RNE
  return (unsigned short)(u >> 16);
}
__device__ __forceinline__ float bf2f(unsigned short s){
  return __builtin_bit_cast(float, ((unsigned)s) << 16);
}
__device__ __forceinline__ unsigned pk(float a, float b){
  return (unsigned)f2bf(a) | ((unsigned)f2bf(b) << 16);
}

// async global->LDS, 16B per lane; dest is wave-uniform base + lane*16 (HW)
__device__ __forceinline__ void gl_lds16(const void* g, void* l){
  __builtin_amdgcn_global_load_lds(
      (const __attribute__((address_space(1))) unsigned*)g,
      (__attribute__((address_space(3))) unsigned*)(unsigned)(unsigned long long)l,
      16, 0, 0);
}

template<int N> __device__ __forceinline__ void vmwait(){
  if      constexpr (N == 16) asm volatile("s_waitcnt vmcnt(16)" ::: "memory");
  else if constexpr (N ==  8) asm volatile("s_waitcnt vmcnt(8)"  ::: "memory");
  else if constexpr (N ==  4) asm volatile("s_waitcnt vmcnt(4)"  ::: "memory");
  else                        asm volatile("s_waitcnt vmcnt(0)"  ::: "memory");
}

// ---------- K0: fused x->bf16 convert (blocks 0..1023) + weight transposes ----------
__global__ void k_prep(const float* __restrict__ x, unsigned short* __restrict__ xb,
                       const float* __restrict__ Wq, unsigned short* __restrict__ Wqt,
                       const float* __restrict__ Wo, unsigned short* __restrict__ Wot){
  int bx = blockIdx.x;
  if (bx < 1024){                      // cvt: 8 elems/thread
    int i = bx * 256 + threadIdx.x;
    const float4* p = (const float4*)x + (size_t)i * 2;
    float4 a = p[0], b = p[1];
    uint4 o;
    o.x = pk(a.x, a.y); o.y = pk(a.z, a.w);
    o.z = pk(b.x, b.y); o.w = pk(b.z, b.w);
    ((uint4*)xb)[i] = o;
    return;
  }
  __shared__ float tile[32][33];
  int i = bx - 1024;                   // 0..767 -> (bxx 0..47, byy 0..15)
  int bxx = i % 48, byy = i / 48;
  const float* W; unsigned short* Wt; int N, n0;
  if (bxx < 32){ W = Wq; Wt = Wqt; N = 1024; n0 = bxx * 32; }
  else         { W = Wo; Wt = Wot; N = 512;  n0 = (bxx - 32) * 32; }
  int k0 = byy * 32;
  int tx = threadIdx.x & 31, ty = threadIdx.x >> 5;   // 32x8
  #pragma unroll
  for (int r = 0; r < 32; r += 8)
    tile[ty + r][tx] = W[(size_t)(k0 + ty + r) * N + n0 + tx];
  __syncthreads();
  #pragma unroll
  for (int r = 0; r < 32; r += 8)
    Wt[(size_t)(n0 + ty + r) * 512 + k0 + tx] = f2bf(tile[tx][ty + r]);
}

// ---------- K1: QKV GEMM, 128x128, 8 waves (2x4), 3-buf depth-2 ----------
// 2 waves/SIMD for m114-style wave overlap. Wave-tile 64x32 (MF=4, NF=2).
// bn<4 : q=silu*scale, k=tanh -> HEAD-MAJOR [bh][s][32]
// bn>=4: V-tile -> LDS transpose -> vt[bh*32+d][s] + vsum_p partials
__launch_bounds__(512)
__global__ void k_gemm0(const unsigned short* __restrict__ A,
                        const unsigned short* __restrict__ Bt,
                        const float* __restrict__ bias,
                        unsigned short* __restrict__ qb,
                        unsigned short* __restrict__ kb,
                        unsigned short* __restrict__ vt,
                        float* __restrict__ vsum_p)
{
  const int K = 512;
  constexpr int NWG = 256;
  __shared__ __align__(16) unsigned short lds[3][256 * 64];   // 3 x 32 KB
  int tid = threadIdx.x;
  int wid = tid >> 6, lane = tid & 63;
  int wm = wid >> 2, wn = wid & 3;       // 2 x 4 wave grid
  int lane15 = lane & 15, laneh = lane >> 4;

  int g = blockIdx.x;
  int gwi = (g & 7) * (NWG / 8) + (g >> 3);
  int bm = gwi / 8, bn = gwi % 8;

  f32x4 acc[4][2] = {};

  int srow_off = lane >> 3;           // 0..7
  int spos     = lane & 7;            // 0..7

  auto STAGE = [&](int buf, int kt){
    int k0 = kt * 64;
    #pragma unroll
    for (int c = 0; c < 4; ++c){
      int g2 = wid * 4 + c;           // 0..31: 16 A groups then 16 B groups
      if (g2 < 16){
        int r = g2 * 8 + srow_off;
        int ch = spos ^ (r & 7);
        gl_lds16(A + (size_t)(bm * 128 + r) * K + k0 + ch * 8, &lds[buf][g2 * 512]);
      } else {
        int gb = g2 - 16;
        int r = gb * 8 + srow_off;
        int ch = spos ^ (r & 7);
        gl_lds16(Bt + (size_t)(bn * 128 + r) * K + k0 + ch * 8, &lds[buf][8192 + gb * 512]);
      }
    }
  };

  auto COMPUTE = [&](int buf){
    #pragma unroll
    for (int kh = 0; kh < 2; ++kh){
      int chunk = kh * 4 + laneh;
      bf16x8 af[4], bfv[2];
      #pragma unroll
      for (int mi = 0; mi < 4; ++mi){
        int row = wm * 64 + mi * 16 + lane15;
        af[mi] = *(const bf16x8*)&lds[buf][row * 64 + (chunk ^ (row & 7)) * 8];
      }
      #pragma unroll
      for (int ni = 0; ni < 2; ++ni){
        int row = wn * 32 + ni * 16 + lane15;
        bfv[ni] = *(const bf16x8*)&lds[buf][8192 + row * 64 + (chunk ^ (row & 7)) * 8];
      }
      #pragma unroll
      for (int mi = 0; mi < 4; ++mi)
        #pragma unroll
        for (int ni = 0; ni < 2; ++ni)
          acc[mi][ni] = __builtin_amdgcn_mfma_f32_16x16x32_bf16(af[mi], bfv[ni], acc[mi][ni], 0, 0, 0);
    }
  };

  STAGE(0, 0);
  STAGE(1, 1);
  #pragma unroll
  for (int kt = 0; kt < 8; ++kt){
    if (kt < 6) STAGE((kt + 2) % 3, kt + 2);
    if (kt < 6)       vmwait<8>();
    else if (kt == 6) vmwait<4>();
    else              vmwait<0>();
    __builtin_amdgcn_s_barrier();
    __builtin_amdgcn_sched_barrier(0);
    COMPUTE(kt % 3);
    __builtin_amdgcn_s_barrier();
    __builtin_amdgcn_sched_barrier(0);
  }

  if (bn >= 4){
    // ---- V path: transpose 128x128 tile in LDS, write vt + vsum partials ----
    unsigned short (*tp)[136] = (unsigned short (*)[136])&lds[0][0];  // 34.8 KB
    #pragma unroll
    for (int mi = 0; mi < 4; ++mi)
      #pragma unroll
      for (int ni = 0; ni < 2; ++ni)
        #pragma unroll
        for (int r = 0; r < 4; ++r){
          int ml = wm * 64 + mi * 16 + laneh * 4 + r;
          int nl = wn * 32 + ni * 16 + lane15;
          tp[nl][ml] = f2bf(acc[mi][ni][r] + bias[bn * 128 + nl]);
        }
    __syncthreads();
    int nl = tid >> 2, q = tid & 3;       // nl 0..127, q covers 32 s each
    int h = (bn - 4) * 4 + (nl >> 5), d = nl & 31;
    int b = bm >> 4, sc = bm & 15;        // 128-row s-chunk within batch
    int bh = b * 16 + h;
    uint4 v4[4];
    float ssum = 0.f;
    #pragma unroll
    for (int p = 0; p < 4; ++p){
      v4[p] = *(const uint4*)&tp[nl][q * 32 + p * 8];
      const unsigned* w = (const unsigned*)&v4[p];
      #pragma unroll
      for (int j = 0; j < 4; ++j)
        ssum += bf2f((unsigned short)(w[j] & 0xffff)) + bf2f((unsigned short)(w[j] >> 16));
    }
    ssum += __shfl_xor(ssum, 1); ssum += __shfl_xor(ssum, 2);
    size_t vtoff = (size_t)(bh * HDIM + d) * SEQ + sc * 128 + q * 32;
    #pragma unroll
    for (int p = 0; p < 4; ++p) *(uint4*)(vt + vtoff + p * 8) = v4[p];
    if (q == 0) vsum_p[(sc * 32 + bh) * HDIM + d] = ssum;
  } else {
    #pragma unroll
    for (int mi = 0; mi < 4; ++mi){
      #pragma unroll
      for (int ni = 0; ni < 2; ++ni){
        #pragma unroll
        for (int r = 0; r < 4; ++r){
          int m = bm * 128 + wm * 64 + mi * 16 + laneh * 4 + r;
          int n = bn * 128 + wn * 32 + ni * 16 + lane15;
          float val = acc[mi][ni][r] + bias[n];
          int b = m >> 11, s = m & 2047;
          int h = n >> 5, d = n & 31;
          size_t idx = ((size_t)(b * 16 + h) * SEQ + s) * HDIM + d;
          float sv = val / (1.0f + __expf(-val)) * QSCALE;      // silu * scale
          float tv = 1.0f - 2.0f / (1.0f + __expf(2.0f * val)); // tanh
          qb[idx] = f2bf(sv);
          kb[idx] = f2bf(tv);
        }
      }
    }
  }
}

// ---------- K4: out-proj GEMM, 64x64, 4 waves, 3-buf depth-2 (R11-proven) ----------
__launch_bounds__(256)
__global__ void k_gemm1(const unsigned short* __restrict__ A,
                        const unsigned short* __restrict__ Bt,
                        const float* __restrict__ bias,
                        const unsigned short* __restrict__ xb,
                        unsigned short* __restrict__ yb)
{
  const int K = 512;
  constexpr int NWG = 512;
  constexpr int LPS = 4;
  __shared__ __align__(16) unsigned short lds[3][128 * 64];
  int tid = threadIdx.x;
  int wid = tid >> 6, lane = tid & 63;
  int wm = wid >> 1, wn = wid & 1;
  int lane15 = lane & 15, laneh = lane >> 4;

  int g = blockIdx.x;
  int gwi = (g & 7) * (NWG / 8) + (g >> 3);
  int bm = gwi / 8, bn = gwi % 8;

  f32x4 acc[2][2] = {};

  int srow_off = lane >> 3;
  int spos     = lane & 7;

  auto STAGE = [&](int buf, int kt){
    int k0 = kt * 64;
    #pragma unroll
    for (int c = 0; c < 2; ++c){
      int cidx = wid * 2 + c;
      int r = cidx * 8 + srow_off;
      int ch = spos ^ (r & 7);
      gl_lds16(A + (size_t)(bm * 64 + r) * K + k0 + ch * 8, &lds[buf][cidx * 512]);
    }
    #pragma unroll
    for (int c = 0; c < 2; ++c){
      int cidx = wid * 2 + c;
      int r = cidx * 8 + srow_off;
      int ch = spos ^ (r & 7);
      gl_lds16(Bt + (size_t)(bn * 64 + r) * K + k0 + ch * 8, &lds[buf][4096 + cidx * 512]);
    }
  };

  auto COMPUTE = [&](int buf){
    #pragma unroll
    for (int kh = 0; kh < 2; ++kh){
      int chunk = kh * 4 + laneh;
      bf16x8 af[2], bfv[2];
      #pragma unroll
      for (int mi = 0; mi < 2; ++mi){
        int row = wm * 32 + mi * 16 + lane15;
        af[mi] = *(const bf16x8*)&lds[buf][row * 64 + (chunk ^ (row & 7)) * 8];
      }
      #pragma unroll
      for (int ni = 0; ni < 2; ++ni){
        int row = wn * 32 + ni * 16 + lane15;
        bfv[ni] = *(const bf16x8*)&lds[buf][4096 + row * 64 + (chunk ^ (row & 7)) * 8];
      }
      #pragma unroll
      for (int mi = 0; mi < 2; ++mi)
        #pragma unroll
        for (int ni = 0; ni < 2; ++ni)
          acc[mi][ni] = __builtin_amdgcn_mfma_f32_16x16x32_bf16(af[mi], bfv[ni], acc[mi][ni], 0, 0, 0);
    }
  };

  STAGE(0, 0);
  STAGE(1, 1);
  #pragma unroll
  for (int kt = 0; kt < 8; ++kt){
    if (kt < 6) STAGE((kt + 2) % 3, kt + 2);
    if (kt < 6)       vmwait<8>();
    else if (kt == 6) vmwait<4>();
    else              vmwait<0>();
    __builtin_amdgcn_s_barrier();
    __builtin_amdgcn_sched_barrier(0);
    COMPUTE(kt % 3);
    __builtin_amdgcn_s_barrier();
    __builtin_amdgcn_sched_barrier(0);
  }

  #pragma unroll
  for (int mi = 0; mi < 2; ++mi){
    #pragma unroll
    for (int ni = 0; ni < 2; ++ni){
      #pragma unroll
      for (int r = 0; r < 4; ++r){
        int m = bm * 64 + wm * 32 + mi * 16 + laneh * 4 + r;
        int n = bn * 64 + wn * 32 + ni * 16 + lane15;
        float val = acc[mi][ni][r] + bias[n];
        size_t idx = (size_t)m * DIMX + n;
        yb[idx] = f2bf(val + bf2f(xb[idx]));
      }
    }
  }
}

// ---------- K3: banded attention (e^s - 1 trick), MFMA, 9 k-tiles ----------
__launch_bounds__(256)
__global__ void k_attn(const unsigned short* __restrict__ qb,
                       const unsigned short* __restrict__ kb,
                       const unsigned short* __restrict__ vt,
                       const float* __restrict__ vsum_p,
                       unsigned short* __restrict__ ao)
{
  __shared__ unsigned short p_lds[4][16][40];   // per-wave P staging, padded
  int tid = threadIdx.x, wid = tid >> 6, lane = tid & 63;
  int lane15 = lane & 15, laneh = lane >> 4;
  int bh = blockIdx.y, b = bh >> 4, h = bh & 15;
  int s0 = blockIdx.x * 64 + wid * 16;

  bf16x8 qf = *(const bf16x8*)(qb + ((size_t)bh * SEQ + s0 + lane15) * HDIM + laneh * 8);
  float vs0 = 0.f, vs1 = 0.f;
  #pragma unroll
  for (int c = 0; c < 16; ++c){
    vs0 += vsum_p[(c * 32 + bh) * HDIM + lane15];
    vs1 += vsum_p[(c * 32 + bh) * HDIM + 16 + lane15];
  }

  f32x4 accv[2] = {};
  float dsum[4] = {0.f, 0.f, 0.f, 0.f};

  // band |i-j|<=64 with i in [s0, s0+16) touches j in [s0-64, s0+80) = 9 tiles
  for (int jt = 0; jt < 9; ++jt){
    int j0 = s0 - 64 + jt * 16;
    int jc = min(max(j0 + lane15, 0), SEQ - 1);
    bf16x8 kf = *(const bf16x8*)(kb + ((size_t)bh * SEQ + jc) * HDIM + laneh * 8);
    f32x4 z = {0.f, 0.f, 0.f, 0.f};
    f32x4 sv = __builtin_amdgcn_mfma_f32_16x16x32_bf16(qf, kf, z, 0, 0, 0);
    #pragma unroll
    for (int r = 0; r < 4; ++r){
      int i = s0 + laneh * 4 + r;
      int j = j0 + lane15;
      int dj = i - j;
      bool inb = (dj <= WIN) && (dj >= -WIN) && (j >= 0) && (j < SEQ);
      float w = inb ? (__expf(sv[r]) - 1.0f) : 0.0f;
      dsum[r] += w;
      p_lds[wid][laneh * 4 + r][(jt & 1) * 16 + lane15] = f2bf(w);
    }
    if (jt & 1){
      int jc0 = j0 - 16;   // 32-wide chunk base
      bf16x8 pa = *(const bf16x8*)&p_lds[wid][lane15][laneh * 8];
      int jv = min(max(jc0 + laneh * 8, 0), SEQ - 8);
      bf16x8 v0 = *(const bf16x8*)(vt + (size_t)(bh * HDIM + lane15) * SEQ + jv);
      bf16x8 v1 = *(const bf16x8*)(vt + (size_t)(bh * HDIM + 16 + lane15) * SEQ + jv);
      accv[0] = __builtin_amdgcn_mfma_f32_16x16x32_bf16(pa, v0, accv[0], 0, 0, 0);
      accv[1] = __builtin_amdgcn_mfma_f32_16x16x32_bf16(pa, v1, accv[1], 0, 0, 0);
    }
  }
  // tail PV for tile 8 (cols 0..15); zero cols 16..31 first
  {
    #pragma unroll
    for (int r = 0; r < 4; ++r)
      p_lds[wid][laneh * 4 + r][16 + lane15] = 0;
    int jc0 = s0 + 64;
    bf16x8 pa = *(const bf16x8*)&p_lds[wid][lane15][laneh * 8];
    int jv = min(max(jc0 + laneh * 8, 0), SEQ - 8);
    bf16x8 v0 = *(const bf16x8*)(vt + (size_t)(bh * HDIM + lane15) * SEQ + jv);
    bf16x8 v1 = *(const bf16x8*)(vt + (size_t)(bh * HDIM + 16 + lane15) * SEQ + jv);
    accv[0] = __builtin_amdgcn_mfma_f32_16x16x32_bf16(pa, v0, accv[0], 0, 0, 0);
    accv[1] = __builtin_amdgcn_mfma_f32_16x16x32_bf16(pa, v1, accv[1], 0, 0, 0);
  }

  #pragma unroll
  for (int r = 0; r < 4; ++r){
    float v = dsum[r];
    v += __shfl_xor(v, 1); v += __shfl_xor(v, 2);
    v += __shfl_xor(v, 4); v += __shfl_xor(v, 8);
    dsum[r] = v;
  }
  #pragma unroll
  for (int r = 0; r < 4; ++r){
    int i = s0 + laneh * 4 + r;
    float dn = (float)SEQ + dsum[r];
    float o0 = (accv[0][r] + vs0) / dn;
    float o1 = (accv[1][r] + vs1) / dn;
    size_t base = (size_t)(b * SEQ + i) * DIMX + h * HDIM;
    ao[base + lane15]      = f2bf(o0);
    ao[base + 16 + lane15] = f2bf(o1);
  }
}

// ---------- K5: LayerNorm over 512 (bf16 in, fp32 out), one wave per row ----------
__global__ void k_ln(const unsigned short* __restrict__ yb, const float* __restrict__ gamma,
                     const float* __restrict__ beta, float* __restrict__ out){
  int wid = threadIdx.x >> 6, lane = threadIdx.x & 63;
  int row = blockIdx.x * 4 + wid;
  uint4 u = *(const uint4*)(yb + (size_t)row * DIMX + lane * 8);
  const unsigned* w = (const unsigned*)&u;
  float v[8];
  #pragma unroll
  for (int j = 0; j < 4; ++j){
    v[2*j]   = bf2f((unsigned short)(w[j] & 0xffff));
    v[2*j+1] = bf2f((unsigned short)(w[j] >> 16));
  }
  float s = 0.f, ss = 0.f;
  #pragma unroll
  for (int j = 0; j < 8; ++j){ s += v[j]; ss += v[j] * v[j]; }
  #pragma unroll
  for (int m = 1; m < 64; m <<= 1){ s += __shfl_xor(s, m); ss += __shfl_xor(ss, m); }
  float mu = s * (1.f / DIMX);
  float var = ss * (1.f / DIMX) - mu * mu;
  float inv = rsqrtf(var + 1e-5f);
  float4 g0 = *(const float4*)(gamma + lane * 8);
  float4 g1 = *(const float4*)(gamma + lane * 8 + 4);
  float4 b0 = *(const float4*)(beta + lane * 8);
  float4 b1 = *(const float4*)(beta + lane * 8 + 4);
  float4 o0, o1;
  o0.x = (v[0] - mu) * inv * g0.x + b0.x; o0.y = (v[1] - mu) * inv * g0.y + b0.y;
  o0.z = (v[2] - mu) * inv * g0.z + b0.z; o0.w = (v[3] - mu) * inv * g0.w + b0.w;
  o1.x = (v[4] - mu) * inv * g1.x + b1.x; o1.y = (v[5] - mu) * inv * g1.y + b1.y;
  o1.z = (v[6] - mu) * inv * g1.z + b1.z; o1.w = (v[7] - mu) * inv * g1.w + b1.w;
  float* op = out + (size_t)row * DIMX + lane * 8;
  *(float4*)op = o0; *(float4*)(op + 4) = o1;
}

extern "C" void kernel_launch(void* const* d_in, const int* in_sizes, int n_in,
                              void* d_out, int out_size, void* d_ws, size_t ws_size,
                              hipStream_t stream){
  const float* x      = (const float*)d_in[0];
  const float* W_qkv  = (const float*)d_in[1];
  const float* b_qkv  = (const float*)d_in[2];
  const float* W_out  = (const float*)d_in[3];
  const float* b_out  = (const float*)d_in[4];
  const float* gamma  = (const float*)d_in[5];
  const float* beta   = (const float*)d_in[6];
  float* out = (float*)d_out;

  char* ws = (char*)d_ws;
  size_t off = 0;
  auto alloc = [&](size_t bytes){ void* p = ws + off; off += (bytes + 255) & ~(size_t)255; return p; };
  unsigned short* xb  = (unsigned short*)alloc((size_t)MTOT * DIMX * 2);
  unsigned short* wqt = (unsigned short*)alloc((size_t)1024 * 512 * 2);
  unsigned short* wot = (unsigned short*)alloc((size_t)512 * 512 * 2);
  unsigned short* qb  = (unsigned short*)alloc((size_t)MTOT * DIMX * 2);
  unsigned short* kb  = (unsigned short*)alloc((size_t)MTOT * DIMX * 2);
  unsigned short* vt  = (unsigned short*)alloc((size_t)32 * HDIM * SEQ * 2);
  float*          vsm = (float*)alloc((size_t)16 * 32 * HDIM * 4);
  unsigned short* ao  = (unsigned short*)alloc((size_t)MTOT * DIMX * 2);
  unsigned short* yb  = (unsigned short*)alloc((size_t)MTOT * DIMX * 2);

  k_prep <<<1792, 256, 0, stream>>>(x, xb, W_qkv, wqt, W_out, wot);
  k_gemm0<<<256, 512, 0, stream>>>(xb, wqt, b_qkv, qb, kb, vt, vsm);
  k_attn <<<dim3(32, 32), 256, 0, stream>>>(qb, kb, vt, vsm, ao);
  k_gemm1<<<512, 256, 0, stream>>>(ao, wot, b_out, xb, yb);
  k_ln   <<<MTOT / 4, 256, 0, stream>>>(yb, gamma, beta, out);
}